// Round 1
// baseline (306.319 us; speedup 1.0000x reference)
//
#include <hip/hip_runtime.h>
#include <math.h>

#define B_ 8
#define C_ 256
#define H_ 31
#define W_ 31
#define T_ 7
#define K_ 49
#define OC_ 147
#define OH_ 25
#define OW_ 25
#define NSP 961   // 31*31
#define OSP 625   // 25*25

// workspace layout (float offsets)
#define N_SRT (B_*NSP*C_)        // 1,968,128
#define OFF_SRT 0
#define N_TMT (B_*K_*C_)         // 100,352
#define OFF_TMT (OFF_SRT + N_SRT)
#define N_WT (2304*OC_)          // 338,688
#define OFF_WT (OFF_TMT + N_TMT)
#define N_OM (B_*OH_*4*160*OW_)  // 3,200,000
#define OFF_OM (OFF_WT + N_WT)

// ---------------- K1: sr (NCHW) -> srT[b][s=y*31+x][c] (channels-last) ----
__global__ __launch_bounds__(256) void k1_transpose_sr(const float* __restrict__ sr,
                                                       float* __restrict__ srT) {
    __shared__ float tile[32][33];
    int bx = blockIdx.x;
    int b = bx / 248;            // 8 ctiles * 31 stiles = 248
    int rem = bx % 248;
    int ct = rem / 31;
    int st = rem % 31;
    int c0 = ct * 32, s0 = st * 32;
    int tx = threadIdx.x, ty = threadIdx.y;
    #pragma unroll
    for (int rr = 0; rr < 4; rr++) {
        int c = c0 + ty + rr * 8;
        int s = s0 + tx;
        if (s < NSP) tile[ty + rr * 8][tx] = sr[(b * C_ + c) * NSP + s];
    }
    __syncthreads();
    #pragma unroll
    for (int rr = 0; rr < 4; rr++) {
        int s = s0 + ty + rr * 8;
        int c = c0 + tx;
        if (s < NSP) srT[((long)b * NSP + s) * C_ + c] = tile[tx][ty + rr * 8];
    }
}

// ---------------- K2: tmpl[b][c][k] -> tmplT[b][k][c] ---------------------
__global__ __launch_bounds__(256) void k2_transpose_tmpl(const float* __restrict__ tm,
                                                         float* __restrict__ tmT) {
    int bx = blockIdx.x;
    int b = bx / K_;
    int k = bx % K_;
    int c = threadIdx.x;
    tmT[(b * K_ + k) * C_ + c] = tm[(b * C_ + c) * K_ + k];
}

// ---------------- K2b: w[oc][c9] -> wT[c9][oc] ----------------------------
__global__ __launch_bounds__(256) void k2b_transpose_w(const float* __restrict__ w,
                                                       float* __restrict__ wT) {
    int i = blockIdx.x * 256 + threadIdx.x;
    if (i < 2304 * OC_) {
        int oc = i % OC_;
        int c9 = i / OC_;
        wT[i] = w[oc * 2304 + c9];
    }
}

// ---------------- K3: conv partials -------------------------------------
// block = (b, out-row i, channel-group cg of 64). 192 threads; lane=oc (<147).
// om layout: [b][i][cg][160][25]
__global__ __launch_bounds__(192) void k3_conv(const float* __restrict__ sr,
                                               const float* __restrict__ wT,
                                               float* __restrict__ om) {
    __shared__ float patch[64][3][28];  // [cc][dy][xi], xi = x+1 in 0..26, zero-padded
    int bx = blockIdx.x;
    int b = bx / 100;
    int rem = bx % 100;
    int i = rem / 4;
    int cg = rem % 4;
    int c0 = cg * 64;
    int tid = threadIdx.x;

    for (int e = tid; e < 64 * 3 * 27; e += 192) {
        int cc = e / 81;
        int r = e % 81;
        int dy = r / 27;
        int xi = r % 27;
        int y = i + dy - 1;     // <= 25 always
        int x = xi - 1;         // -1..25
        float v = 0.f;
        if (y >= 0 && x >= 0) v = sr[((b * C_ + c0 + cc) * H_ + y) * W_ + x];
        patch[cc][dy][xi] = v;
    }
    __syncthreads();

    int oc = tid;
    if (oc < OC_) {
        float acc[25];
        #pragma unroll
        for (int j = 0; j < 25; j++) acc[j] = 0.f;
        for (int cc = 0; cc < 64; cc++) {
            #pragma unroll
            for (int dy = 0; dy < 3; dy++) {
                int c9base = ((c0 + cc) * 3 + dy) * 3;
                float wv0 = wT[(c9base + 0) * OC_ + oc];
                float wv1 = wT[(c9base + 1) * OC_ + oc];
                float wv2 = wT[(c9base + 2) * OC_ + oc];
                float r_[27];
                #pragma unroll
                for (int xi = 0; xi < 27; xi++) r_[xi] = patch[cc][dy][xi];
                #pragma unroll
                for (int j = 0; j < 25; j++)
                    acc[j] += r_[j] * wv0 + r_[j + 1] * wv1 + r_[j + 2] * wv2;
            }
        }
        long base = ((long)((b * OH_ + i) * 4 + cg) * 160 + oc) * OW_;
        #pragma unroll
        for (int j = 0; j < 25; j++) om[base + j] = acc[j];
    }
}

// ---------------- K4: offsets/mask + bilinear gather + reduce -------------
// block = (b, i, j), thread = channel c.
__global__ __launch_bounds__(256) void k4_gather(const float* __restrict__ srT,
                                                 const float* __restrict__ tmT,
                                                 const float* __restrict__ om,
                                                 const float* __restrict__ bias,
                                                 float* __restrict__ out) {
    __shared__ float lom[160];
    __shared__ float ly0[K_], lx0[K_], lwy[K_], lwx[K_], lm[K_];
    int bx = blockIdx.x;
    int b = bx / OSP;
    int rem = bx % OSP;
    int i = rem / OW_;
    int j = rem % OW_;
    int t = threadIdx.x;

    if (t < OC_) {
        float s = bias[t];
        #pragma unroll
        for (int cg = 0; cg < 4; cg++)
            s += om[((long)((b * OH_ + i) * 4 + cg) * 160 + t) * OW_ + j];
        lom[t] = s;
    }
    __syncthreads();

    if (t < K_) {
        float oy = lom[t];
        float ox = lom[K_ + t];
        float mk = 1.f / (1.f + expf(-lom[2 * K_ + t]));
        float ys = (float)(i + t / T_) + oy;
        float xs = (float)(j + t % T_) + ox;
        float y0 = floorf(ys);
        float x0 = floorf(xs);
        ly0[t] = y0;
        lx0[t] = x0;
        lwy[t] = ys - y0;
        lwx[t] = xs - x0;
        lm[t] = mk;
    }
    __syncthreads();

    int c = t;
    float acc = 0.f;
    const float* srTb = srT + (long)b * NSP * C_;
    const float* tmTb = tmT + (long)b * K_ * C_;
    for (int k = 0; k < K_; k++) {
        float y0 = ly0[k], x0 = lx0[k];
        float wy = lwy[k], wx = lwx[k], m = lm[k];
        float y1 = y0 + 1.f, x1 = x0 + 1.f;
        bool vy0 = (y0 >= 0.f) && (y0 <= 30.f);
        bool vy1 = (y1 >= 0.f) && (y1 <= 30.f);
        bool vx0 = (x0 >= 0.f) && (x0 <= 30.f);
        bool vx1 = (x1 >= 0.f) && (x1 <= 30.f);
        int iy0 = min(max((int)y0, 0), 30);
        int iy1 = min(max((int)y1, 0), 30);
        int ix0 = min(max((int)x0, 0), 30);
        int ix1 = min(max((int)x1, 0), 30);
        float v00 = 0.f, v01 = 0.f, v10 = 0.f, v11 = 0.f;
        // conditions are uniform across the block (depend only on k) -> no divergence
        if (vy0 && vx0) v00 = srTb[(iy0 * W_ + ix0) * C_ + c];
        if (vy0 && vx1) v01 = srTb[(iy0 * W_ + ix1) * C_ + c];
        if (vy1 && vx0) v10 = srTb[(iy1 * W_ + ix0) * C_ + c];
        if (vy1 && vx1) v11 = srTb[(iy1 * W_ + ix1) * C_ + c];
        float bil = (1.f - wy) * ((1.f - wx) * v00 + wx * v01)
                  + wy * ((1.f - wx) * v10 + wx * v11);
        acc += tmTb[k * C_ + c] * m * bil;
    }
    out[((long)(b * C_ + c) * OH_ + i) * OW_ + j] = acc;
}

extern "C" void kernel_launch(void* const* d_in, const int* in_sizes, int n_in,
                              void* d_out, int out_size, void* d_ws, size_t ws_size,
                              hipStream_t stream) {
    const float* sr = (const float*)d_in[0];
    const float* tm = (const float*)d_in[1];
    const float* w  = (const float*)d_in[2];
    const float* bs = (const float*)d_in[3];
    float* out = (float*)d_out;
    float* Wp = (float*)d_ws;
    float* srT = Wp + OFF_SRT;
    float* tmT = Wp + OFF_TMT;
    float* wT  = Wp + OFF_WT;
    float* om  = Wp + OFF_OM;

    k1_transpose_sr<<<8 * 8 * 31, dim3(32, 8), 0, stream>>>(sr, srT);
    k2_transpose_tmpl<<<B_ * K_, 256, 0, stream>>>(tm, tmT);
    k2b_transpose_w<<<(2304 * OC_ + 255) / 256, 256, 0, stream>>>(w, wT);
    k3_conv<<<B_ * OH_ * 4, 192, 0, stream>>>(sr, wT, om);
    k4_gather<<<B_ * OSP, 256, 0, stream>>>(srT, tmT, om, bs, out);
}

// Round 2
// 293.714 us; speedup vs baseline: 1.0429x; 1.0429x over previous
//
#include <hip/hip_runtime.h>
#include <hip/hip_bf16.h>
#include <math.h>

#define B_ 8
#define C_ 256
#define H_ 31
#define W_ 31
#define T_ 7
#define K_ 49
#define OC_ 147
#define OCP 160
#define OH_ 25
#define OW_ 25
#define NSP 961   // 31*31
#define OSP 625   // 25*25
#define KK_ 2304  // 256*9
#define KS_ 576   // 64*9  (per channel-group)
#define KSP 584   // padded Bt row (in bf16 elems)

typedef __bf16 bf16x8 __attribute__((ext_vector_type(8)));
typedef float f32x4 __attribute__((ext_vector_type(4)));

// workspace layout (byte offsets)
#define BYTES_SRT (B_*NSP*C_*2)          // 3,936,256
#define BYTES_TMT (B_*K_*C_*2)           // 200,704
#define BYTES_WTM (OCP*KK_*2)            // 737,280
#define OFFB_SRT 0
#define OFFB_TMT (OFFB_SRT + BYTES_SRT)
#define OFFB_WTM (OFFB_TMT + BYTES_TMT)
#define OFFB_OM  (OFFB_WTM + BYTES_WTM)  // 4,874,240 (4B aligned)

// ---------------- K1: sr (NCHW fp32) -> srT[b][s][c] bf16 -----------------
__global__ __launch_bounds__(256) void k1_transpose_sr(const float* __restrict__ sr,
                                                       __hip_bfloat16* __restrict__ srT) {
    __shared__ float tile[32][33];
    int bx = blockIdx.x;
    int b = bx / 248;            // 8 ctiles * 31 stiles
    int rem = bx % 248;
    int ct = rem / 31;
    int st = rem % 31;
    int c0 = ct * 32, s0 = st * 32;
    int tx = threadIdx.x, ty = threadIdx.y;
    #pragma unroll
    for (int rr = 0; rr < 4; rr++) {
        int c = c0 + ty + rr * 8;
        int s = s0 + tx;
        if (s < NSP) tile[ty + rr * 8][tx] = sr[(b * C_ + c) * NSP + s];
    }
    __syncthreads();
    #pragma unroll
    for (int rr = 0; rr < 4; rr++) {
        int s = s0 + ty + rr * 8;
        int c = c0 + tx;
        if (s < NSP) srT[((long)b * NSP + s) * C_ + c] = __float2bfloat16(tile[tx][ty + rr * 8]);
    }
}

// ---------------- K2: tmpl[b][c][k] -> tmplT[b][k][c] bf16 ----------------
__global__ __launch_bounds__(256) void k2_transpose_tmpl(const float* __restrict__ tm,
                                                         __hip_bfloat16* __restrict__ tmT) {
    int bx = blockIdx.x;
    int b = bx / K_;
    int k = bx % K_;
    int c = threadIdx.x;
    tmT[(b * K_ + k) * C_ + c] = __float2bfloat16(tm[(b * C_ + c) * K_ + k]);
}

// ---------------- K2b: w[oc][c9] fp32 -> wTm[ocp][c9] bf16 (zero-pad oc) --
__global__ __launch_bounds__(256) void k2b_cast_w(const float* __restrict__ w,
                                                  __hip_bfloat16* __restrict__ wTm) {
    int i = blockIdx.x * 256 + threadIdx.x;
    if (i < OCP * KK_) {
        int oc = i / KK_;
        float v = (oc < OC_) ? w[i] : 0.f;   // same layout, row-padded
        wTm[i] = __float2bfloat16(v);
    }
}

// ---------------- K3: conv via bf16 MFMA im2col GEMM ----------------------
// block = (b, out-row i, channel-group cg of 64). 256 threads = 4 waves.
// om layout: [b][i][cg][160][25] fp32
__global__ __launch_bounds__(256) void k3_mfma(const float* __restrict__ sr,
                                               const __hip_bfloat16* __restrict__ wTm,
                                               float* __restrict__ om) {
    __shared__ __hip_bfloat16 patch[64][3][28];  // [cc][dy][xi], xi=x+1 in 0..26
    __shared__ __hip_bfloat16 Bt[32][KSP];       // im2col^T: [n][kk], kk padded
    int bx = blockIdx.x;
    int b = bx / 100;
    int rem = bx % 100;
    int i = rem / 4;
    int cg = rem % 4;
    int c0 = cg * 64;
    int tid = threadIdx.x;

    // phase 1: patch (bf16)
    for (int e = tid; e < 64 * 3 * 27; e += 256) {
        int cc = e / 81;
        int r = e % 81;
        int dy = r / 27;
        int xi = r % 27;
        int y = i + dy - 1;
        int x = xi - 1;
        float v = 0.f;
        if (y >= 0 && x >= 0) v = sr[((b * C_ + c0 + cc) * H_ + y) * W_ + x];
        patch[cc][dy][xi] = __float2bfloat16(v);
    }
    __syncthreads();

    // phase 2: Bt[n][kk] = patch[kk/9][(kk%9)/3][n + kk%3]; zero pad n>=25, kk>=576
    for (int e = tid; e < 32 * KSP; e += 256) {
        int n = e / KSP;
        int kk = e % KSP;
        __hip_bfloat16 v = __float2bfloat16(0.f);
        if (kk < KS_ && n < OW_) {
            int cc = kk / 9;
            int r9 = kk % 9;
            v = patch[cc][r9 / 3][n + r9 % 3];
        }
        Bt[n][kk] = v;
    }
    __syncthreads();

    // phase 3: GEMM. wave w: nf = w&1, mh = w>>1.
    int wv = tid >> 6;
    int l = tid & 63;
    int nf = wv & 1, mh = wv >> 1;
    int lr = l & 15, lg = l >> 4;

    f32x4 acc[5] = {};
    const bf16x8* btp = reinterpret_cast<const bf16x8*>(&Bt[nf * 16 + lr][0]);
    const bf16x8* ap = reinterpret_cast<const bf16x8*>(wTm);
    int arow_base = mh * 80 + lr;             // + mf*16
    int acol_base = cg * 72;                  // (cg*576)/8; + ks*4 + lg

    for (int ks = 0; ks < 18; ++ks) {
        bf16x8 bfrag = btp[ks * 4 + lg];
        #pragma unroll
        for (int mf = 0; mf < 5; ++mf) {
            int row = arow_base + mf * 16;
            bf16x8 afrag = ap[row * 288 + acol_base + ks * 4 + lg];
            acc[mf] = __builtin_amdgcn_mfma_f32_16x16x32_bf16(afrag, bfrag, acc[mf], 0, 0, 0);
        }
    }

    // store: D row = oc (m), col = n (j). col=lane&15, row=4*(lane>>4)+reg.
    int j = nf * 16 + lr;
    if (j < OW_) {
        long base = (long)((b * OH_ + i) * 4 + cg) * (OCP * OW_);
        #pragma unroll
        for (int mf = 0; mf < 5; ++mf) {
            #pragma unroll
            for (int r = 0; r < 4; ++r) {
                int oc = mh * 80 + mf * 16 + lg * 4 + r;
                om[base + oc * OW_ + j] = acc[mf][r];
            }
        }
    }
}

// ---------------- K4: offsets/mask + bilinear gather + reduce -------------
__global__ __launch_bounds__(256) void k4_gather(const __hip_bfloat16* __restrict__ srT,
                                                 const __hip_bfloat16* __restrict__ tmT,
                                                 const float* __restrict__ om,
                                                 const float* __restrict__ bias,
                                                 float* __restrict__ out) {
    __shared__ float lom[OCP];
    __shared__ float ly0[K_], lx0[K_], lwy[K_], lwx[K_], lm[K_];
    int bx = blockIdx.x;
    int b = bx / OSP;
    int rem = bx % OSP;
    int i = rem / OW_;
    int j = rem % OW_;
    int t = threadIdx.x;

    if (t < OC_) {
        float s = bias[t];
        #pragma unroll
        for (int cg = 0; cg < 4; cg++)
            s += om[(long)((b * OH_ + i) * 4 + cg) * (OCP * OW_) + t * OW_ + j];
        lom[t] = s;
    }
    __syncthreads();

    if (t < K_) {
        float oy = lom[t];
        float ox = lom[K_ + t];
        float mk = 1.f / (1.f + expf(-lom[2 * K_ + t]));
        float ys = (float)(i + t / T_) + oy;
        float xs = (float)(j + t % T_) + ox;
        float y0 = floorf(ys);
        float x0 = floorf(xs);
        ly0[t] = y0;
        lx0[t] = x0;
        lwy[t] = ys - y0;
        lwx[t] = xs - x0;
        lm[t] = mk;
    }
    __syncthreads();

    int c = t;
    float acc = 0.f;
    const __hip_bfloat16* srTb = srT + (long)b * NSP * C_;
    const __hip_bfloat16* tmTb = tmT + (long)b * K_ * C_;
    for (int k = 0; k < K_; k++) {
        float y0 = ly0[k], x0 = lx0[k];
        float wy = lwy[k], wx = lwx[k], m = lm[k];
        float y1 = y0 + 1.f, x1 = x0 + 1.f;
        bool vy0 = (y0 >= 0.f) && (y0 <= 30.f);
        bool vy1 = (y1 >= 0.f) && (y1 <= 30.f);
        bool vx0 = (x0 >= 0.f) && (x0 <= 30.f);
        bool vx1 = (x1 >= 0.f) && (x1 <= 30.f);
        int iy0 = min(max((int)y0, 0), 30);
        int iy1 = min(max((int)y1, 0), 30);
        int ix0 = min(max((int)x0, 0), 30);
        int ix1 = min(max((int)x1, 0), 30);
        float v00 = 0.f, v01 = 0.f, v10 = 0.f, v11 = 0.f;
        // conditions uniform across block (depend only on k) -> no divergence
        if (vy0 && vx0) v00 = __bfloat162float(srTb[(iy0 * W_ + ix0) * C_ + c]);
        if (vy0 && vx1) v01 = __bfloat162float(srTb[(iy0 * W_ + ix1) * C_ + c]);
        if (vy1 && vx0) v10 = __bfloat162float(srTb[(iy1 * W_ + ix0) * C_ + c]);
        if (vy1 && vx1) v11 = __bfloat162float(srTb[(iy1 * W_ + ix1) * C_ + c]);
        float bil = (1.f - wy) * ((1.f - wx) * v00 + wx * v01)
                  + wy * ((1.f - wx) * v10 + wx * v11);
        acc += __bfloat162float(tmTb[k * C_ + c]) * m * bil;
    }
    out[((long)(b * C_ + c) * OH_ + i) * OW_ + j] = acc;
}

extern "C" void kernel_launch(void* const* d_in, const int* in_sizes, int n_in,
                              void* d_out, int out_size, void* d_ws, size_t ws_size,
                              hipStream_t stream) {
    const float* sr = (const float*)d_in[0];
    const float* tm = (const float*)d_in[1];
    const float* w  = (const float*)d_in[2];
    const float* bs = (const float*)d_in[3];
    float* out = (float*)d_out;
    char* wsb = (char*)d_ws;
    __hip_bfloat16* srT = (__hip_bfloat16*)(wsb + OFFB_SRT);
    __hip_bfloat16* tmT = (__hip_bfloat16*)(wsb + OFFB_TMT);
    __hip_bfloat16* wTm = (__hip_bfloat16*)(wsb + OFFB_WTM);
    float* om = (float*)(wsb + OFFB_OM);

    k1_transpose_sr<<<8 * 8 * 31, dim3(32, 8), 0, stream>>>(sr, srT);
    k2_transpose_tmpl<<<B_ * K_, 256, 0, stream>>>(tm, tmT);
    k2b_cast_w<<<(OCP * KK_ + 255) / 256, 256, 0, stream>>>(w, wTm);
    k3_mfma<<<B_ * OH_ * 4, 256, 0, stream>>>(sr, wTm, om);
    k4_gather<<<B_ * OSP, 256, 0, stream>>>(srT, tmT, om, bs, out);
}

// Round 4
// 164.970 us; speedup vs baseline: 1.8568x; 1.7804x over previous
//
#include <hip/hip_runtime.h>
#include <hip/hip_bf16.h>
#include <math.h>

#define B_ 8
#define C_ 256
#define H_ 31
#define W_ 31
#define T_ 7
#define K_ 49
#define OC_ 147
#define OCP 160
#define OH_ 25
#define OW_ 25
#define NSP 961   // 31*31
#define OSP 625   // 25*25
#define KK_ 2304  // 256*9
#define KS_ 576   // 64*9  (per channel-group)
#define KSP 584   // padded Bt row (bf16 elems, 16B-aligned rows)

typedef __bf16 bf16x8 __attribute__((ext_vector_type(8)));
typedef float f32x4 __attribute__((ext_vector_type(4)));

// workspace layout (byte offsets, all 16B aligned)
#define OFFB_SRT 0                      // 3,936,256  srT bf16 [b][s][c]
#define OFFB_TMT 3936256                // 200,704    tmT bf16 [b][k][c]
#define OFFB_WPK 4136960                // 737,280    wPk bf16 fragment-order
#define OFFB_BIAS 4874240               // 640        biasP f32 [160]
#define OFFB_OM  4874880                // 12,800,000 om f32 [b][i][cg][j=25][oc=160]

__device__ inline float blo(unsigned u) { return __uint_as_float(u << 16); }
__device__ inline float bhi(unsigned u) { return __uint_as_float(u & 0xffff0000u); }

// ---------------- K1: sr (NCHW fp32) -> srT[b][s][c] bf16 -----------------
__global__ __launch_bounds__(256) void k1_transpose_sr(const float* __restrict__ sr,
                                                       __hip_bfloat16* __restrict__ srT) {
    __shared__ float tile[32][33];
    int bx = blockIdx.x;
    int b = bx / 248;
    int rem = bx % 248;
    int ct = rem / 31;
    int st = rem % 31;
    int c0 = ct * 32, s0 = st * 32;
    int tx = threadIdx.x, ty = threadIdx.y;
    #pragma unroll
    for (int rr = 0; rr < 4; rr++) {
        int c = c0 + ty + rr * 8;
        int s = s0 + tx;
        if (s < NSP) tile[ty + rr * 8][tx] = sr[(b * C_ + c) * NSP + s];
    }
    __syncthreads();
    #pragma unroll
    for (int rr = 0; rr < 4; rr++) {
        int s = s0 + ty + rr * 8;
        int c = c0 + tx;
        if (s < NSP) srT[((long)b * NSP + s) * C_ + c] = __float2bfloat16(tile[tx][ty + rr * 8]);
    }
}

// ---------------- K2: tmpl[b][c][k] -> tmplT[b][k][c] bf16 ----------------
__global__ __launch_bounds__(256) void k2_transpose_tmpl(const float* __restrict__ tm,
                                                         __hip_bfloat16* __restrict__ tmT) {
    int bx = blockIdx.x;
    int b = bx / K_;
    int k = bx % K_;
    int c = threadIdx.x;
    tmT[(b * K_ + k) * C_ + c] = __float2bfloat16(tm[(b * C_ + c) * K_ + k]);
}

// ---------------- K2b: w -> wPk in MFMA-fragment order --------------------
// frag id fid = ((cg*2+mh)*18+ks)*5+mf ; per lane l: 8 bf16.
// source: oc = mh*80+mf*16+(l&15), col = cg*576 + ks*32 + (l>>4)*8 + j
__global__ __launch_bounds__(256) void k2b_pack_w(const float* __restrict__ w,
                                                  __hip_bfloat16* __restrict__ wPk) {
    int i = blockIdx.x * 256 + threadIdx.x;   // 46080 total
    if (i >= 46080) return;
    int l = i & 63;
    int fid = i >> 6;
    int mf = fid % 5;
    int ks = (fid / 5) % 18;
    int mh = (fid / 90) % 2;
    int cg = fid / 180;
    int oc = mh * 80 + mf * 16 + (l & 15);
    int col0 = cg * 576 + ks * 32 + (l >> 4) * 8;
    bf16x8 v;
    #pragma unroll
    for (int j = 0; j < 8; j++) {
        float f = (oc < OC_) ? w[oc * KK_ + col0 + j] : 0.f;
        v[j] = (__bf16)f;
    }
    *reinterpret_cast<bf16x8*>(wPk + ((long)i << 3)) = v;
}

// ---------------- K2c: pad bias to 160 ------------------------------------
__global__ void k2c_pad_bias(const float* __restrict__ bias, float* __restrict__ biasP) {
    int t = threadIdx.x;
    if (t < OCP) biasP[t] = (t < OC_) ? bias[t] : 0.f;
}

// ---------------- K3: conv via bf16 MFMA im2col GEMM ----------------------
// block = (b, out-row i, channel-group cg). 256 threads = 4 waves.
// om layout: [b][i][cg][j=25][oc=160] fp32  (j-major so k4 reads coalesced)
__global__ __launch_bounds__(256) void k3_mfma(const float* __restrict__ sr,
                                               const __hip_bfloat16* __restrict__ wPk,
                                               float* __restrict__ om) {
    __shared__ __hip_bfloat16 patch[64][3][28];
    __shared__ __hip_bfloat16 Bt[32][KSP];
    int bx = blockIdx.x;
    int b = bx / 100;
    int rem = bx % 100;
    int i = rem / 4;
    int cg = rem % 4;
    int c0 = cg * 64;
    int tid = threadIdx.x;

    for (int e = tid; e < 64 * 3 * 27; e += 256) {
        int cc = e / 81;
        int r = e % 81;
        int dy = r / 27;
        int xi = r % 27;
        int y = i + dy - 1;
        int x = xi - 1;
        float v = 0.f;
        if (y >= 0 && x >= 0) v = sr[((b * C_ + c0 + cc) * H_ + y) * W_ + x];
        patch[cc][dy][xi] = __float2bfloat16(v);
    }
    __syncthreads();

    for (int e = tid; e < 32 * KSP; e += 256) {
        int n = e / KSP;
        int kk = e % KSP;
        __hip_bfloat16 v = __float2bfloat16(0.f);
        if (kk < KS_ && n < OW_) {
            int cc = kk / 9;
            int r9 = kk % 9;
            v = patch[cc][r9 / 3][n + r9 % 3];
        }
        Bt[n][kk] = v;
    }
    __syncthreads();

    int wv = tid >> 6;
    int l = tid & 63;
    int nf = wv & 1, mh = wv >> 1;
    int lr = l & 15, lg = l >> 4;

    f32x4 acc[5] = {};
    const bf16x8* btp = reinterpret_cast<const bf16x8*>(&Bt[nf * 16 + lr][0]);
    const bf16x8* apk = reinterpret_cast<const bf16x8*>(wPk);
    // fragment base for (cg, mh): coalesced — consecutive lanes read consecutive 16B
    int fbase = ((cg * 2 + mh) * 18) * 5;   // + ks*5 + mf, then *64 + l

    for (int ks = 0; ks < 18; ++ks) {
        bf16x8 bfrag = btp[ks * 4 + lg];
        #pragma unroll
        for (int mf = 0; mf < 5; ++mf) {
            bf16x8 afrag = apk[((fbase + ks * 5 + mf) << 6) + l];
            acc[mf] = __builtin_amdgcn_mfma_f32_16x16x32_bf16(afrag, bfrag, acc[mf], 0, 0, 0);
        }
    }

    // store transposed: om[...][j][oc]; D col=lane&15 -> j, row=4*(lane>>4)+reg -> oc
    int j = nf * 16 + lr;
    if (j < OW_) {
        float* ob = om + (long)((b * OH_ + i) * 4 + cg) * (OW_ * OCP) + j * OCP + mh * 80 + lg * 4;
        #pragma unroll
        for (int mf = 0; mf < 5; ++mf)
            *reinterpret_cast<f32x4*>(ob + mf * 16) = acc[mf];
    }
}

// ---------------- K4: offsets/mask + bilinear gather + reduce -------------
// block = (b,i,j); 128 threads; thread t handles channels 2t, 2t+1 (packed u32)
__global__ __launch_bounds__(128) void k4_gather(const __hip_bfloat16* __restrict__ srT,
                                                 const __hip_bfloat16* __restrict__ tmT,
                                                 const float* __restrict__ om,
                                                 const float* __restrict__ biasP,
                                                 float* __restrict__ out) {
    __shared__ float lom[OCP];
    __shared__ int4 loff[K_];
    __shared__ float4 lwt[K_];
    int bx = blockIdx.x;
    int b = bx / OSP;
    int rem = bx % OSP;
    int i = rem / OW_;
    int j = rem % OW_;
    int t = threadIdx.x;

    if (t < 40) {
        f32x4 s = *reinterpret_cast<const f32x4*>(biasP + t * 4);
        const float* ob = om + (long)(b * OH_ + i) * (4 * OW_ * OCP) + j * OCP + t * 4;
        #pragma unroll
        for (int cg = 0; cg < 4; cg++)
            s += *reinterpret_cast<const f32x4*>(ob + cg * (OW_ * OCP));
        *reinterpret_cast<f32x4*>(lom + t * 4) = s;
    }
    __syncthreads();

    if (t < K_) {
        float oy = lom[t];
        float ox = lom[K_ + t];
        float mk = 1.f / (1.f + expf(-lom[2 * K_ + t]));
        float ys = (float)(i + t / T_) + oy;
        float xs = (float)(j + t % T_) + ox;
        float y0f = floorf(ys);
        float x0f = floorf(xs);
        float wy = ys - y0f, wx = xs - x0f;
        bool vy0 = (y0f >= 0.f) && (y0f <= 30.f);
        bool vy1 = (y0f >= -1.f) && (y0f <= 29.f);
        bool vx0 = (x0f >= 0.f) && (x0f <= 30.f);
        bool vx1 = (x0f >= -1.f) && (x0f <= 29.f);
        int iy = (int)y0f;
        int ix = (int)x0f;
        int cy0 = min(max(iy, 0), 30), cy1 = min(max(iy + 1, 0), 30);
        int cx0 = min(max(ix, 0), 30), cx1 = min(max(ix + 1, 0), 30);
        float a00 = (1.f - wy) * (1.f - wx), a01 = (1.f - wy) * wx;
        float a10 = wy * (1.f - wx), a11 = wy * wx;
        lwt[t] = make_float4(mk * a00 * (float)(vy0 && vx0),
                             mk * a01 * (float)(vy0 && vx1),
                             mk * a10 * (float)(vy1 && vx0),
                             mk * a11 * (float)(vy1 && vx1));
        loff[t] = make_int4((cy0 * W_ + cx0) * 128, (cy0 * W_ + cx1) * 128,
                            (cy1 * W_ + cx0) * 128, (cy1 * W_ + cx1) * 128);
    }
    __syncthreads();

    const unsigned* srU = reinterpret_cast<const unsigned*>(srT) + (long)b * NSP * 128;
    const unsigned* tmU = reinterpret_cast<const unsigned*>(tmT) + (long)b * K_ * 128;
    float acc0 = 0.f, acc1 = 0.f;
    for (int k = 0; k < K_; ++k) {
        int4 o = loff[k];
        float4 wv = lwt[k];
        unsigned u00 = srU[o.x + t];
        unsigned u01 = srU[o.y + t];
        unsigned u10 = srU[o.z + t];
        unsigned u11 = srU[o.w + t];
        unsigned tu = tmU[(k << 7) + t];
        float s0 = wv.x * blo(u00);
        s0 = fmaf(wv.y, blo(u01), s0);
        s0 = fmaf(wv.z, blo(u10), s0);
        s0 = fmaf(wv.w, blo(u11), s0);
        float s1 = wv.x * bhi(u00);
        s1 = fmaf(wv.y, bhi(u01), s1);
        s1 = fmaf(wv.z, bhi(u10), s1);
        s1 = fmaf(wv.w, bhi(u11), s1);
        acc0 = fmaf(blo(tu), s0, acc0);
        acc1 = fmaf(bhi(tu), s1, acc1);
    }
    long ob = ((long)(b * C_ + 2 * t) * OH_ + i) * OW_ + j;
    out[ob] = acc0;
    out[ob + (long)OH_ * OW_] = acc1;
}

extern "C" void kernel_launch(void* const* d_in, const int* in_sizes, int n_in,
                              void* d_out, int out_size, void* d_ws, size_t ws_size,
                              hipStream_t stream) {
    const float* sr = (const float*)d_in[0];
    const float* tm = (const float*)d_in[1];
    const float* w  = (const float*)d_in[2];
    const float* bs = (const float*)d_in[3];
    float* out = (float*)d_out;
    char* wsb = (char*)d_ws;
    __hip_bfloat16* srT = (__hip_bfloat16*)(wsb + OFFB_SRT);
    __hip_bfloat16* tmT = (__hip_bfloat16*)(wsb + OFFB_TMT);
    __hip_bfloat16* wPk = (__hip_bfloat16*)(wsb + OFFB_WPK);
    float* biasP = (float*)(wsb + OFFB_BIAS);
    float* om = (float*)(wsb + OFFB_OM);

    k1_transpose_sr<<<8 * 8 * 31, dim3(32, 8), 0, stream>>>(sr, srT);
    k2_transpose_tmpl<<<B_ * K_, 256, 0, stream>>>(tm, tmT);
    k2b_pack_w<<<180, 256, 0, stream>>>(w, wPk);
    k2c_pad_bias<<<1, OCP, 0, stream>>>(bs, biasP);
    k3_mfma<<<B_ * OH_ * 4, 256, 0, stream>>>(sr, wPk, om);
    k4_gather<<<B_ * OSP, 128, 0, stream>>>(srT, tmT, om, biasP, out);
}

// Round 5
// 134.749 us; speedup vs baseline: 2.2733x; 1.2243x over previous
//
#include <hip/hip_runtime.h>
#include <hip/hip_bf16.h>
#include <math.h>

#define B_ 8
#define C_ 256
#define H_ 31
#define W_ 31
#define T_ 7
#define K_ 49
#define OC_ 147
#define OCP 160
#define OH_ 25
#define OW_ 25
#define NSP 961   // 31*31
#define OSP 625   // 25*25
#define KK_ 2304  // 256*9

typedef __bf16 bf16x8 __attribute__((ext_vector_type(8)));
typedef float f32x4 __attribute__((ext_vector_type(4)));

// workspace layout (byte offsets, all 16B aligned)
#define OFFB_SRT 0                      // 3,936,256  srT bf16 [b][s][c]
#define OFFB_TMT 3936256                // 200,704    tmT bf16 [b][k][c]
#define OFFB_WPK 4136960                // 737,280    wPk bf16 fragment-order (9-shift)
#define OFFB_BIAS 4874240               // 640        biasP f32 [160]
#define OFFB_OM  4874880                // 12,800,000 om f32 [b][i][cg][j=25][oc=160]

__device__ inline float blo(unsigned u) { return __uint_as_float(u << 16); }
__device__ inline float bhi(unsigned u) { return __uint_as_float(u & 0xffff0000u); }

// ---------------- K1: sr (NCHW fp32) -> srT[b][s][c] bf16 -----------------
__global__ __launch_bounds__(256) void k1_transpose_sr(const float* __restrict__ sr,
                                                       __hip_bfloat16* __restrict__ srT) {
    __shared__ float tile[32][33];
    int bx = blockIdx.x;
    int b = bx / 248;
    int rem = bx % 248;
    int ct = rem / 31;
    int st = rem % 31;
    int c0 = ct * 32, s0 = st * 32;
    int tx = threadIdx.x, ty = threadIdx.y;
    #pragma unroll
    for (int rr = 0; rr < 4; rr++) {
        int c = c0 + ty + rr * 8;
        int s = s0 + tx;
        if (s < NSP) tile[ty + rr * 8][tx] = sr[(b * C_ + c) * NSP + s];
    }
    __syncthreads();
    #pragma unroll
    for (int rr = 0; rr < 4; rr++) {
        int s = s0 + ty + rr * 8;
        int c = c0 + tx;
        if (s < NSP) srT[((long)b * NSP + s) * C_ + c] = __float2bfloat16(tile[tx][ty + rr * 8]);
    }
}

// ---------------- K2: tmpl[b][c][k] -> tmplT[b][k][c] bf16 ----------------
__global__ __launch_bounds__(256) void k2_transpose_tmpl(const float* __restrict__ tm,
                                                         __hip_bfloat16* __restrict__ tmT) {
    int bx = blockIdx.x;
    int b = bx / K_;
    int k = bx % K_;
    int c = threadIdx.x;
    tmT[(b * K_ + k) * C_ + c] = __float2bfloat16(tm[(b * C_ + c) * K_ + k]);
}

// ---------------- K2b: w -> wPk in 9-shift MFMA-fragment order (+bias pad)
// fid = (((cg*9 + s)*2 + ks)*2 + mh)*5 + mf ; lane l holds 8 bf16.
// oc = mh*80 + mf*16 + (l&15);  c = cg*64 + ks*32 + (l>>4)*8 + jj;  src w[oc][c][s]
__global__ __launch_bounds__(256) void k2b_pack_w(const float* __restrict__ w,
                                                  const float* __restrict__ bias,
                                                  __hip_bfloat16* __restrict__ wPk,
                                                  float* __restrict__ biasP) {
    if (blockIdx.x == 0 && threadIdx.x < OCP)
        biasP[threadIdx.x] = (threadIdx.x < OC_) ? bias[threadIdx.x] : 0.f;
    int i = blockIdx.x * 256 + threadIdx.x;   // 46080 total
    if (i >= 46080) return;
    int l = i & 63;
    int fid = i >> 6;                         // 0..719
    int mf = fid % 5;
    int mh = (fid / 5) % 2;
    int ks = (fid / 10) % 2;
    int s  = (fid / 20) % 9;
    int cg = fid / 180;
    int oc = mh * 80 + mf * 16 + (l & 15);
    int cbase = cg * 64 + ks * 32 + (l >> 4) * 8;
    bf16x8 v;
    #pragma unroll
    for (int jj = 0; jj < 8; jj++) {
        float f = (oc < OC_) ? w[oc * KK_ + (cbase + jj) * 9 + s] : 0.f;
        v[jj] = (__bf16)f;
    }
    *reinterpret_cast<bf16x8*>(wPk + ((long)i << 3)) = v;
}

// ---------------- K3: conv via 9-shift bf16 MFMA GEMM ---------------------
// block = (b, out-row i, channel-group cg); 128 threads = 2 waves (mh 0/1).
// LDS: raw sr slab rows y=i-1..i+1, xi=0..26, 64 ch; row stride 72 bf16 (144B).
// om layout: [b][i][cg][j=25][oc=160] fp32
__global__ __launch_bounds__(128) void k3_mfma(const __hip_bfloat16* __restrict__ srT,
                                               const __hip_bfloat16* __restrict__ wPk,
                                               float* __restrict__ om) {
    __shared__ __hip_bfloat16 lds[88 * 72];   // 81 real rows + margin for j>=25 lanes
    int sb = (blockIdx.x & 7) * 100 + (blockIdx.x >> 3);  // XCD-chunked
    int b = sb / 100;
    int rem = sb % 100;
    int i = rem / 4;
    int cg = rem % 4;
    int tid = threadIdx.x;

    // stage 3 x 27 x 64c slab (zero-pad y<0 and x<0), coalesced 16B ops
    const __hip_bfloat16* srTb = srT + (long)b * NSP * C_ + cg * 64;
    for (int o = tid; o < 648; o += 128) {
        int ryx = o >> 3;
        int c8 = (o & 7) * 8;
        int yy = ryx / 27;
        int xi = ryx - yy * 27;
        int y = i - 1 + yy;
        int x = xi - 1;
        bf16x8 v = {};
        if (y >= 0 && x >= 0)
            v = *reinterpret_cast<const bf16x8*>(srTb + (y * W_ + x) * C_ + c8);
        *reinterpret_cast<bf16x8*>(&lds[ryx * 72 + c8]) = v;
    }
    __syncthreads();

    int wv = tid >> 6;        // mh
    int l = tid & 63;
    int lr = l & 15, lg = l >> 4;

    f32x4 acc[5][2] = {};
    const bf16x8* apk = reinterpret_cast<const bf16x8*>(wPk);

    #pragma unroll
    for (int dy = 0; dy < 3; ++dy) {
        #pragma unroll
        for (int dx = 0; dx < 3; ++dx) {
            int s = dy * 3 + dx;
            #pragma unroll
            for (int ks = 0; ks < 2; ++ks) {
                int e0 = (dy * 27 + dx + lr) * 72 + ks * 32 + lg * 8;
                bf16x8 b0 = *reinterpret_cast<const bf16x8*>(&lds[e0]);
                bf16x8 b1 = *reinterpret_cast<const bf16x8*>(&lds[e0 + 16 * 72]);
                const bf16x8* ap = apk + (long)((((cg * 9 + s) * 2 + ks) * 2 + wv) * 5) * 64 + l;
                #pragma unroll
                for (int mf = 0; mf < 5; ++mf) {
                    bf16x8 a = ap[mf * 64];
                    acc[mf][0] = __builtin_amdgcn_mfma_f32_16x16x32_bf16(a, b0, acc[mf][0], 0, 0, 0);
                    acc[mf][1] = __builtin_amdgcn_mfma_f32_16x16x32_bf16(a, b1, acc[mf][1], 0, 0, 0);
                }
            }
        }
    }

    // store: D col=lane&15 -> j, row=4*(lane>>4)+reg -> oc within mf tile
    #pragma unroll
    for (int nf = 0; nf < 2; ++nf) {
        int j = nf * 16 + lr;
        if (j < OW_) {
            float* ob = om + (long)((b * OH_ + i) * 4 + cg) * (OW_ * OCP) + j * OCP + wv * 80 + lg * 4;
            #pragma unroll
            for (int mf = 0; mf < 5; ++mf)
                *reinterpret_cast<f32x4*>(ob + mf * 16) = acc[mf][nf];
        }
    }
}

// ---------------- K4: offsets/mask + bilinear gather + reduce -------------
// block = (b,i,j); 128 threads; thread t handles channels 2t, 2t+1 (packed u32)
__global__ __launch_bounds__(128) void k4_gather(const __hip_bfloat16* __restrict__ srT,
                                                 const __hip_bfloat16* __restrict__ tmT,
                                                 const float* __restrict__ om,
                                                 const float* __restrict__ biasP,
                                                 float* __restrict__ out) {
    __shared__ float lom[OCP];
    __shared__ int4 loff[K_];
    __shared__ float4 lwt[K_];
    int sb = (blockIdx.x & 7) * 625 + (blockIdx.x >> 3);  // XCD-chunked (5000/8=625)
    int b = sb / OSP;
    int rem = sb % OSP;
    int i = rem / OW_;
    int j = rem % OW_;
    int t = threadIdx.x;

    if (t < 40) {
        f32x4 s = *reinterpret_cast<const f32x4*>(biasP + t * 4);
        const float* ob = om + (long)(b * OH_ + i) * (4 * OW_ * OCP) + j * OCP + t * 4;
        #pragma unroll
        for (int cg = 0; cg < 4; cg++)
            s += *reinterpret_cast<const f32x4*>(ob + cg * (OW_ * OCP));
        *reinterpret_cast<f32x4*>(lom + t * 4) = s;
    }
    __syncthreads();

    if (t < K_) {
        float oy = lom[t];
        float ox = lom[K_ + t];
        float mk = 1.f / (1.f + expf(-lom[2 * K_ + t]));
        float ys = (float)(i + t / T_) + oy;
        float xs = (float)(j + t % T_) + ox;
        float y0f = floorf(ys);
        float x0f = floorf(xs);
        float wy = ys - y0f, wx = xs - x0f;
        bool vy0 = (y0f >= 0.f) && (y0f <= 30.f);
        bool vy1 = (y0f >= -1.f) && (y0f <= 29.f);
        bool vx0 = (x0f >= 0.f) && (x0f <= 30.f);
        bool vx1 = (x0f >= -1.f) && (x0f <= 29.f);
        int iy = (int)y0f;
        int ix = (int)x0f;
        int cy0 = min(max(iy, 0), 30), cy1 = min(max(iy + 1, 0), 30);
        int cx0 = min(max(ix, 0), 30), cx1 = min(max(ix + 1, 0), 30);
        float a00 = (1.f - wy) * (1.f - wx), a01 = (1.f - wy) * wx;
        float a10 = wy * (1.f - wx), a11 = wy * wx;
        lwt[t] = make_float4(mk * a00 * (float)(vy0 && vx0),
                             mk * a01 * (float)(vy0 && vx1),
                             mk * a10 * (float)(vy1 && vx0),
                             mk * a11 * (float)(vy1 && vx1));
        loff[t] = make_int4((cy0 * W_ + cx0) * 128, (cy0 * W_ + cx1) * 128,
                            (cy1 * W_ + cx0) * 128, (cy1 * W_ + cx1) * 128);
    }
    __syncthreads();

    const unsigned* srU = reinterpret_cast<const unsigned*>(srT) + (long)b * NSP * 128;
    const unsigned* tmU = reinterpret_cast<const unsigned*>(tmT) + (long)b * K_ * 128;
    float acc0 = 0.f, acc1 = 0.f;
    for (int k = 0; k < K_; ++k) {
        int4 o = loff[k];
        float4 wv = lwt[k];
        unsigned u00 = srU[o.x + t];
        unsigned u01 = srU[o.y + t];
        unsigned u10 = srU[o.z + t];
        unsigned u11 = srU[o.w + t];
        unsigned tu = tmU[(k << 7) + t];
        float s0 = wv.x * blo(u00);
        s0 = fmaf(wv.y, blo(u01), s0);
        s0 = fmaf(wv.z, blo(u10), s0);
        s0 = fmaf(wv.w, blo(u11), s0);
        float s1 = wv.x * bhi(u00);
        s1 = fmaf(wv.y, bhi(u01), s1);
        s1 = fmaf(wv.z, bhi(u10), s1);
        s1 = fmaf(wv.w, bhi(u11), s1);
        acc0 = fmaf(blo(tu), s0, acc0);
        acc1 = fmaf(bhi(tu), s1, acc1);
    }
    long ob = ((long)(b * C_ + 2 * t) * OH_ + i) * OW_ + j;
    out[ob] = acc0;
    out[ob + (long)OH_ * OW_] = acc1;
}

extern "C" void kernel_launch(void* const* d_in, const int* in_sizes, int n_in,
                              void* d_out, int out_size, void* d_ws, size_t ws_size,
                              hipStream_t stream) {
    const float* sr = (const float*)d_in[0];
    const float* tm = (const float*)d_in[1];
    const float* w  = (const float*)d_in[2];
    const float* bs = (const float*)d_in[3];
    float* out = (float*)d_out;
    char* wsb = (char*)d_ws;
    __hip_bfloat16* srT = (__hip_bfloat16*)(wsb + OFFB_SRT);
    __hip_bfloat16* tmT = (__hip_bfloat16*)(wsb + OFFB_TMT);
    __hip_bfloat16* wPk = (__hip_bfloat16*)(wsb + OFFB_WPK);
    float* biasP = (float*)(wsb + OFFB_BIAS);
    float* om = (float*)(wsb + OFFB_OM);

    k1_transpose_sr<<<8 * 8 * 31, dim3(32, 8), 0, stream>>>(sr, srT);
    k2_transpose_tmpl<<<B_ * K_, 256, 0, stream>>>(tm, tmT);
    k2b_pack_w<<<180, 256, 0, stream>>>(w, bs, wPk, biasP);
    k3_mfma<<<B_ * OH_ * 4, 128, 0, stream>>>(srT, wPk, om);
    k4_gather<<<B_ * OSP, 128, 0, stream>>>(srT, tmT, om, biasP, out);
}